// Round 12
// baseline (2369.801 us; speedup 1.0000x reference)
//
#include <hip/hip_runtime.h>
#include <hip/hip_bf16.h>

using u16 = unsigned short;
using u32 = unsigned int;
using bf16x8 = __attribute__((ext_vector_type(8))) __bf16;
using f32x4  = __attribute__((ext_vector_type(4))) float;
using u32x2  = __attribute__((ext_vector_type(2))) u32;
using u32x4  = __attribute__((ext_vector_type(4))) u32;

#define GLP(p) ((const __attribute__((address_space(1))) void*)(p))
#define LDSP(p) ((__attribute__((address_space(3))) void*)(p))

__device__ __forceinline__ float bf2f(u16 u) {
    union { float f; u32 i; } v; v.i = ((u32)u) << 16; return v.f;
}
__device__ __forceinline__ u16 f2bf(float f) {
    union { float f; u32 i; } v; v.f = f;
    u32 r = v.i + 0x7FFFu + ((v.i >> 16) & 1u);
    return (u16)(r >> 16);
}

// LLC-coherent primitives (bypass L1+L2; coherence point = LLC). Proven R4-R10.
__device__ __forceinline__ u32 ld_sc01_u32(const u32* p) {
    u32 v;
    asm volatile("global_load_dword %0, %1, off sc0 sc1\n\ts_waitcnt vmcnt(0)"
                 : "=v"(v) : "v"(p) : "memory");
    return v;
}
__device__ __forceinline__ void st_sc01_u32(u32* p, u32 v) {
    asm volatile("global_store_dword %0, %1, off sc0 sc1" :: "v"(p), "v"(v) : "memory");
}
__device__ __forceinline__ void st_sc01_u32x2(u32* p, u32x2 v) {
    asm volatile("global_store_dwordx2 %0, %1, off sc0 sc1" :: "v"(p), "v"(v) : "memory");
}
__device__ __forceinline__ void st_sc01_u16(u16* p, u16 v) {
    asm volatile("global_store_short %0, %1, off sc0 sc1" :: "v"(p), "v"(v) : "memory");
}

__device__ __forceinline__ float sigm(float x) {
    return __builtin_amdgcn_rcpf(1.f + __expf(-x));
}
__device__ __forceinline__ float tanh_fast(float x) {
    float e = __expf(-2.f * x);
    return (1.f - e) * __builtin_amdgcn_rcpf(1.f + e);
}

// ---------------- gather: X0[t*32+n][k] = bf16(emb[x[n][t]][k]) ----------------
__global__ void k_gather(const int* __restrict__ x, const float* __restrict__ emb,
                         u16* __restrict__ X0) {
    int gid = blockIdx.x * blockDim.x + threadIdx.x;
    if (gid >= 16384 * 256) return;
    int e4 = gid << 2;
    int m = e4 >> 10, k = e4 & 1023;
    int t = m >> 5, n = m & 31;
    int tok = x[n * 512 + t];
    float4 v = *reinterpret_cast<const float4*>(emb + ((size_t)tok << 10) + k);
    ushort4 o;
    o.x = f2bf(v.x); o.y = f2bf(v.y); o.z = f2bf(v.z); o.w = f2bf(v.w);
    *reinterpret_cast<ushort4*>(X0 + (size_t)e4) = o;
}

// ---------------- fp32 -> bf16 bulk convert ----------------
__global__ void k_f32bf16(const float* __restrict__ s, u16* __restrict__ d, int n4) {
    int gid = blockIdx.x * blockDim.x + threadIdx.x;
    if (gid >= n4) return;
    float4 v = reinterpret_cast<const float4*>(s)[gid];
    ushort4 o;
    o.x = f2bf(v.x); o.y = f2bf(v.y); o.z = f2bf(v.z); o.w = f2bf(v.w);
    reinterpret_cast<ushort4*>(d)[gid] = o;
}

// ---------------- GRU scan body R11: epoch-tagged h transport ----------------
// hbuf element = u32 { bf16 h (lo16), epoch tag (hi16) }. Producer at step t
// stores tag t+1 fire-and-forget. Consumer stager wave w reloads its 64-col
// slice (exec-masked, stale chunks only) until all tags == t -- detection and
// data transfer are the same load. No flags, no store-acks, no drain barriers.
template<int LAYER>
__device__ __forceinline__ void gru_body(char* smem, int d, int wg,
    const u16* __restrict__ Gi, const u16* __restrict__ Whh_l,
    const float* __restrict__ bhh_l, u32* __restrict__ hbuf,   // [2][2][32][512] u32
    u16* __restrict__ X1, float* __restrict__ hid, float* __restrict__ outp,
    u32* __restrict__ xflags, const u32* __restrict__ gdone)
{
    char* hS          = smem;                                // 32768 B (swizzled h)
    float (*ghs)[196] = (float(*)[196])(smem + 32768);       // 25088 B
    u16 (*gis)[208]   = (u16(*)[208])(smem + 57856);         // 13312 B
    float* bhh_s      = (float*)(smem + 71168);              //   768 B
    const int tid = threadIdx.x;
    const int lane = tid & 63, w = tid >> 6;                 // w in [0,12)
    const int j0 = wg * 64;
    const int g = w >> 2;
    const int lr = lane & 15, lk = lane >> 4;

    if (tid < 192) {
        int g2 = tid >> 6, jj = tid & 63;
        bhh_s[tid] = bhh_l[d * 1536 + g2 * 512 + j0 + jj];
    }
    // pin W_hh fragments (16 k-tiles x 4 VGPRs = 64 VGPR/thread)
    bf16x8 wf[16];
    {
        const int joff = (w & 3) * 16;
        const u16* wr = Whh_l + (size_t)(d * 1536 + g * 512 + j0 + joff + lr) * 512 + lk * 8;
        #pragma unroll
        for (int kt = 0; kt < 16; ++kt)
            wf[kt] = *reinterpret_cast<const bf16x8*>(wr + kt * 32);
    }
    __syncthreads();

    // h-staging geometry (waves 0-7): lane -> 8-col chunk x 4 row groups
    const int colu = w * 64 + (lane & 7) * 8;   // u32 col
    const int rb = lane >> 3;                   // row base 0..7
    const int cb = colu * 2;                    // byte col offset in hS (bf16 pairs)
    // gi-staging base chunk (waves 8-11)
    const int ci0 = (tid - 512) * 3;

    float hpv[4] = {0.f, 0.f, 0.f, 0.f};
    u32 g_seen = 0;

    for (int t = 0; t < 512; ++t) {
        // ==== A: staging (stagers poll epoch-tagged h; waves 8-11 load gi) ====
        if (w < 8) {
            const u32* hb = hbuf + ((size_t)d * 2 + ((t + 1) & 1)) * 16384;
            const u32 expt = (u32)t << 16;
            u32x4 va[4][2];
            bool fresh[4] = {false, false, false, false};
            long long T0 = __builtin_amdgcn_s_memrealtime();
            for (;;) {
                #pragma unroll
                for (int c = 0; c < 4; ++c) {
                    if (!fresh[c]) {
                        const u32* p = hb + (size_t)(rb + c * 8) * 512 + colu;
                        asm volatile("global_load_dwordx4 %0, %1, off sc0 sc1"
                                     : "=v"(va[c][0]) : "v"(p));
                        asm volatile("global_load_dwordx4 %0, %1, off sc0 sc1"
                                     : "=v"(va[c][1]) : "v"(p + 4));
                    }
                }
                asm volatile("s_waitcnt vmcnt(0)" ::: "memory");
                bool all4 = true;
                #pragma unroll
                for (int c = 0; c < 4; ++c) {
                    if (!fresh[c]) {
                        u32 xv = 0;
                        #pragma unroll
                        for (int i = 0; i < 4; ++i) {
                            xv |= (va[c][0][i] ^ expt);
                            xv |= (va[c][1][i] ^ expt);
                        }
                        fresh[c] = ((xv & 0xFFFF0000u) == 0);
                    }
                    all4 = all4 && fresh[c];
                }
                if (__all(all4)) break;
                if (__builtin_amdgcn_s_memrealtime() - T0 > 2000000) break;  // 20 ms escape
            }
            // repack low halves -> bf16 pairs, swizzled hS write
            #pragma unroll
            for (int c = 0; c < 4; ++c) {
                int row = rb + c * 8;
                u32x4 pk;
                pk[0] = (va[c][0][0] & 0xFFFFu) | (va[c][0][1] << 16);
                pk[1] = (va[c][0][2] & 0xFFFFu) | (va[c][0][3] << 16);
                pk[2] = (va[c][1][0] & 0xFFFFu) | (va[c][1][1] << 16);
                pk[3] = (va[c][1][2] & 0xFFFFu) | (va[c][1][3] << 16);
                *reinterpret_cast<u32x4*>(hS + row * 1024 + (cb ^ ((row & 15) << 4))) = pk;
            }
        } else {
            u32 yneed = (u32)(t >> 2);
            if (g_seen <= yneed) {
                const u32* gp = gdone + yneed;
                long long T0 = __builtin_amdgcn_s_memrealtime();
                while (ld_sc01_u32(gp) == 0) {
                    __builtin_amdgcn_s_sleep(1);
                    if (__builtin_amdgcn_s_memrealtime() - T0 > 2000000) break;  // 20 ms
                }
                g_seen = yneed + 1;
            }
            u32x4 gq[3];
            int nbs[3], gcs[3];
            #pragma unroll
            for (int i = 0; i < 3; ++i) {
                int ci = ci0 + i;
                nbs[i] = ci / 24; gcs[i] = ci % 24;
                const u16* gp = Gi + (size_t)(t * 32 + nbs[i]) * 3072 + d * 1536
                              + (gcs[i] >> 3) * 512 + j0 + (gcs[i] & 7) * 8;
                asm volatile("global_load_dwordx4 %0, %1, off sc0 sc1"
                             : "=v"(gq[i]) : "v"(gp));
            }
            asm volatile("s_waitcnt vmcnt(0)" ::: "memory");
            #pragma unroll
            for (int i = 0; i < 3; ++i)
                *reinterpret_cast<u32x4*>(&gis[nbs[i]][gcs[i] * 8]) = gq[i];
        }
        __syncthreads();   // B1: hS + gis staged

        // ==== B: MFMA + ghs ====
        f32x4 acc0 = {0.f, 0.f, 0.f, 0.f}, acc1 = acc0;
        #pragma unroll
        for (int kt = 0; kt < 16; ++kt) {
            int boff = (lk * 16 + kt * 64) ^ (lr << 4);
            bf16x8 a0 = *reinterpret_cast<const bf16x8*>(hS + lr * 1024 + boff);
            bf16x8 a1 = *reinterpret_cast<const bf16x8*>(hS + (16 + lr) * 1024 + boff);
            acc0 = __builtin_amdgcn_mfma_f32_16x16x32_bf16(a0, wf[kt], acc0, 0, 0, 0);
            acc1 = __builtin_amdgcn_mfma_f32_16x16x32_bf16(a1, wf[kt], acc1, 0, 0, 0);
        }
        int colg = w * 16 + lr;
        float bv = bhh_s[colg];
        #pragma unroll
        for (int q = 0; q < 4; ++q) {
            ghs[lk * 4 + q][colg]      = acc0[q] + bv;
            ghs[16 + lk * 4 + q][colg] = acc1[q] + bv;
        }
        __syncthreads();   // B2: ghs ready

        // ==== C: gates + h'; tagged-h store + outputs, all fire-and-forget ====
        u32* hbw = hbuf + ((size_t)d * 2 + (t & 1)) * 16384;
        const u32 tagn = (u32)(t + 1) << 16;
        #pragma unroll
        for (int rep = 0; rep < 2; ++rep) {
            int e2 = (rep == 0) ? tid : tid + 256;
            if (rep == 0 || tid >= 512) {
                int jp = (e2 & 31) * 2, nb = e2 >> 5;
                int rr = rep * 2;
                float r0 = sigm(bf2f(gis[nb][jp])          + ghs[nb][jp]);
                float r1 = sigm(bf2f(gis[nb][jp + 1])      + ghs[nb][jp + 1]);
                float z0 = sigm(bf2f(gis[nb][64 + jp])     + ghs[nb][64 + jp]);
                float z1 = sigm(bf2f(gis[nb][64 + jp + 1]) + ghs[nb][64 + jp + 1]);
                float n0 = tanh_fast(bf2f(gis[nb][128 + jp])     + r0 * ghs[nb][128 + jp]);
                float n1 = tanh_fast(bf2f(gis[nb][128 + jp + 1]) + r1 * ghs[nb][128 + jp + 1]);
                float hv0 = (1.f - z0) * n0 + z0 * hpv[rr];
                float hv1 = (1.f - z1) * n1 + z1 * hpv[rr + 1];
                hpv[rr] = hv0; hpv[rr + 1] = hv1;
                u16 b0 = f2bf(hv0), b1 = f2bf(hv1);
                u32x2 pp = { (u32)b0 | tagn, (u32)b1 | tagn };
                st_sc01_u32x2(hbw + (size_t)nb * 512 + j0 + jp, pp);
                float2 hf; hf.x = hv0; hf.y = hv1;
                *reinterpret_cast<float2*>(hid + ((size_t)(t * 4 + LAYER * 2 + d) * 32 + nb) * 512
                                           + j0 + jp) = hf;
                if (LAYER == 0) {
                    st_sc01_u32((u32*)(X1 + (size_t)(t * 32 + nb) * 1024 + (size_t)d * 512 + j0 + jp),
                                (u32)b0 | ((u32)b1 << 16));
                } else {
                    *reinterpret_cast<float2*>(outp + ((size_t)nb * 512 + t) * 1024
                                               + (size_t)d * 512 + j0 + jp) = hf;
                }
            }
        }
        // ==== step-end barrier: LDS ordering only (no VMEM drain) ====
        if (LAYER == 0 && (t & 3) == 3) {
            asm volatile("s_waitcnt vmcnt(0)" ::: "memory");  // X1 at LLC
            __syncthreads();
            if (tid == 17)
                st_sc01_u32(xflags + (d * 8 + wg) * 32, (u32)(t + 1));
        } else {
            __builtin_amdgcn_sched_barrier(0);
            __builtin_amdgcn_s_barrier();
            __builtin_amdgcn_sched_barrier(0);
        }
    }
}

// ---------------- chaser GEMM (48 WGs per phase; waves 0-5 compute) ----------
__device__ __forceinline__ void chaser_body(char* smem, int cw,
    const u16* __restrict__ A, const u16* __restrict__ B,
    const float* __restrict__ bias, u16* __restrict__ Gi,
    const u32* __restrict__ xflags, u32* __restrict__ cnt, u32* __restrict__ done)
{
    u16* As = (u16*)smem;            // 16 KB
    u16* Bs = (u16*)(smem + 16384);  // 12 KB
    const int tid = threadIdx.x;
    const int lane = tid & 63, wid = tid >> 6;
    const int wm = wid & 1, wn = wid >> 1;
    const int lr = lane & 15, lk = lane >> 4;

    for (int T = cw; T < 4096; T += 48) {
        const int y = T >> 5, x = T & 31;
        if (xflags && tid < 16) {
            const u32* fp = xflags + tid * 32;
            u32 target = 4u * (u32)y + 4u;
            long long T0 = __builtin_amdgcn_s_memrealtime();
            while (ld_sc01_u32(fp) < target) {
                __builtin_amdgcn_s_sleep(4);
                if (__builtin_amdgcn_s_memrealtime() - T0 > 2000000) break;  // 20 ms
            }
        }
        __syncthreads();

        f32x4 zero = {0.f, 0.f, 0.f, 0.f};
        f32x4 acc[4][2];
        #pragma unroll
        for (int i = 0; i < 4; ++i) { acc[i][0] = zero; acc[i][1] = zero; }

        for (int k0 = 0; k0 < 1024; k0 += 64) {
            #pragma unroll
            for (int r = 0; r < 5; ++r) {
                int c = wid * 5 + r;               // wid>=6 -> c>=30 -> skipped
                if (c < 16) {
                    int o = c * 1024 + lane * 16;
                    int row = o >> 7, kb = o & 127;
                    int kbs = kb ^ ((row & 7) << 4);
                    const char* s = (const char*)A + ((size_t)(y * 128 + row) * 1024 + k0) * 2 + kbs;
                    __builtin_amdgcn_global_load_lds(GLP(s), LDSP((char*)As + c * 1024), 16, 0, 0);
                } else if (c < 28) {
                    int c2 = c - 16;
                    int o = c2 * 1024 + lane * 16;
                    int row = o >> 7, kb = o & 127;
                    int kbs = kb ^ ((row & 7) << 4);
                    const char* s = (const char*)B + ((size_t)(x * 96 + row) * 1024 + k0) * 2 + kbs;
                    __builtin_amdgcn_global_load_lds(GLP(s), LDSP((char*)Bs + c2 * 1024), 16, 0, 0);
                }
            }
            __syncthreads();
            if (wid < 6) {
                #pragma unroll
                for (int kk = 0; kk < 2; ++kk) {
                    bf16x8 af[4], bfr[2];
                    int kb = kk * 64 + lk * 16;
                    #pragma unroll
                    for (int i = 0; i < 4; ++i) {
                        int rowA = wm * 64 + i * 16 + lr;
                        af[i] = *reinterpret_cast<const bf16x8*>((const char*)As + rowA * 128 + (kb ^ ((rowA & 7) << 4)));
                    }
                    #pragma unroll
                    for (int j = 0; j < 2; ++j) {
                        int rowB = wn * 32 + j * 16 + lr;
                        bfr[j] = *reinterpret_cast<const bf16x8*>((const char*)Bs + rowB * 128 + (kb ^ ((rowB & 7) << 4)));
                    }
                    #pragma unroll
                    for (int i = 0; i < 4; ++i)
                        #pragma unroll
                        for (int j = 0; j < 2; ++j)
                            acc[i][j] = __builtin_amdgcn_mfma_f32_16x16x32_bf16(af[i], bfr[j], acc[i][j], 0, 0, 0);
                }
            }
            __syncthreads();
        }
        if (wid < 6) {
            #pragma unroll
            for (int j = 0; j < 2; ++j) {
                int col = x * 96 + wn * 32 + j * 16 + lr;
                float bv = bias[col];
                #pragma unroll
                for (int i = 0; i < 4; ++i) {
                    int rowb = y * 128 + wm * 64 + i * 16 + lk * 4;
                    #pragma unroll
                    for (int q = 0; q < 4; ++q)
                        st_sc01_u16(Gi + (size_t)(rowb + q) * 3072 + col, f2bf(acc[i][j][q] + bv));
                }
            }
        }
        asm volatile("s_waitcnt vmcnt(0)" ::: "memory");
        __syncthreads();
        if (tid == 0) {
            u32 old = __hip_atomic_fetch_add(&cnt[y], 1u, __ATOMIC_RELAXED,
                                             __HIP_MEMORY_SCOPE_AGENT);
            if (old == 31u)
                st_sc01_u32((u32*)&done[y], 1u);
        }
    }
}

// -------- fused: gru0(16) | gemm0-chaser(48) | gemm1-chaser(48) | gru1(16) ----
__global__ __launch_bounds__(768, 3) void k_fused(
    u16* __restrict__ Gi,
    const u16* __restrict__ X0, const u16* __restrict__ Wih,
    const float* __restrict__ b_ih,
    const u16* __restrict__ Whh, const float* __restrict__ bhh,
    u32* __restrict__ hbuf0, u32* __restrict__ hbuf1,
    u16* __restrict__ X1,
    float* __restrict__ hid, float* __restrict__ outp,
    u32* __restrict__ xflags,
    u32* __restrict__ g0cnt, u32* __restrict__ g0done,
    u32* __restrict__ g1cnt, u32* __restrict__ g1done)
{
    __shared__ __align__(16) char smem[71936];
    int bid = blockIdx.x;
    if (bid < 16) {
        gru_body<0>(smem, bid >> 3, bid & 7, Gi, Whh, bhh, hbuf0,
                    X1, hid, outp, xflags, g0done);
    } else if (bid < 64) {
        chaser_body(smem, bid - 16, X0, Wih, b_ih, Gi, nullptr, g0cnt, g0done);
    } else if (bid < 112) {
        chaser_body(smem, bid - 64, X1, Wih + (size_t)3072 * 1024, b_ih + 3072,
                    Gi, xflags, g1cnt, g1done);
    } else {
        int b = bid - 112;
        gru_body<1>(smem, b >> 3, b & 7, Gi, Whh + (size_t)3072 * 512, bhh + 3072,
                    hbuf1, nullptr, hid, outp, nullptr, g1done);
    }
}

extern "C" void kernel_launch(void* const* d_in, const int* in_sizes, int n_in,
                              void* d_out, int out_size, void* d_ws, size_t ws_size,
                              hipStream_t stream) {
    const int*   x    = (const int*)d_in[0];
    const float* emb  = (const float*)d_in[1];
    const float* w_ih = (const float*)d_in[2];
    const float* w_hh = (const float*)d_in[3];
    const float* b_ih = (const float*)d_in[4];
    const float* b_hh = (const float*)d_in[5];
    float* outp = (float*)d_out;
    float* hid  = outp + (size_t)32 * 512 * 1024;

    char* ws = (char*)d_ws;
    u16* X0     = (u16*)(ws);                  //  33,554,432 B
    u16* X1     = (u16*)(ws + 33554432);       //  33,554,432 B
    u16* Wih    = (u16*)(ws + 67108864);       //  12,582,912 B
    u16* Whh    = (u16*)(ws + 79691776);       //   6,291,456 B
    u16* Gi     = (u16*)(ws + 85983232);       // 100,663,296 B
    u32* hbuf0  = (u32*)(ws + 186646528);      //     262,144 B  u32[2][2][32][512]
    u32* hbuf1  = (u32*)(ws + 186908672);      //     262,144 B
    u32* xflags = (u32*)(ws + 187170816);      //       2,048 B  [2][8][32]
    u32* g0cnt  = (u32*)(ws + 187172864);      //         512 B
    u32* g0done = (u32*)(ws + 187173376);      //         512 B
    u32* g1cnt  = (u32*)(ws + 187173888);      //         512 B
    u32* g1done = (u32*)(ws + 187174400);      //         512 B

    k_gather<<<16384, 256, 0, stream>>>(x, emb, X0);
    k_f32bf16<<<(1572864 + 255) / 256, 256, 0, stream>>>(w_ih, Wih, 1572864);
    k_f32bf16<<<( 786432 + 255) / 256, 256, 0, stream>>>(w_hh, Whh, 786432);

    // zero hbuf0|hbuf1|xflags|g0cnt|g0done|g1cnt|g1done (contiguous; tags=0)
    (void)hipMemsetAsync(hbuf0, 0, 528384, stream);

    // fused pipeline: gru0 | gemm0-chaser | gemm1-chaser | gru1
    k_fused<<<128, 768, 0, stream>>>(Gi, X0, Wih, b_ih, Whh, b_hh,
                                     hbuf0, hbuf1, X1, hid, outp,
                                     xflags, g0cnt, g0done, g1cnt, g1done);
}

// Round 13
// 1982.105 us; speedup vs baseline: 1.1956x; 1.1956x over previous
//
#include <hip/hip_runtime.h>
#include <hip/hip_bf16.h>

using u16 = unsigned short;
using u32 = unsigned int;
using bf16x8 = __attribute__((ext_vector_type(8))) __bf16;
using f32x4  = __attribute__((ext_vector_type(4))) float;
using u32x4  = __attribute__((ext_vector_type(4))) u32;

#define GLP(p) ((const __attribute__((address_space(1))) void*)(p))
#define LDSP(p) ((__attribute__((address_space(3))) void*)(p))

__device__ __forceinline__ float bf2f(u16 u) {
    union { float f; u32 i; } v; v.i = ((u32)u) << 16; return v.f;
}
__device__ __forceinline__ u16 f2bf(float f) {
    union { float f; u32 i; } v; v.f = f;
    u32 r = v.i + 0x7FFFu + ((v.i >> 16) & 1u);
    return (u16)(r >> 16);
}

// LLC-coherent primitives (bypass L1+L2; coherence point = LLC). Proven R4-R11.
__device__ __forceinline__ u32 ld_sc01_u32(const u32* p) {
    u32 v;
    asm volatile("global_load_dword %0, %1, off sc0 sc1\n\ts_waitcnt vmcnt(0)"
                 : "=v"(v) : "v"(p) : "memory");
    return v;
}
__device__ __forceinline__ void st_sc01_u32(u32* p, u32 v) {
    asm volatile("global_store_dword %0, %1, off sc0 sc1" :: "v"(p), "v"(v) : "memory");
}
__device__ __forceinline__ void st_sc01_u16(u16* p, u16 v) {
    asm volatile("global_store_short %0, %1, off sc0 sc1" :: "v"(p), "v"(v) : "memory");
}
__device__ __forceinline__ void st_sc01_u32x4(u16* p, u32x4 v) {
    asm volatile("global_store_dwordx4 %0, %1, off sc0 sc1" :: "v"(p), "v"(v) : "memory");
}

__device__ __forceinline__ float sigm(float x) {
    return __builtin_amdgcn_rcpf(1.f + __expf(-x));
}
__device__ __forceinline__ float tanh_fast(float x) {
    float e = __expf(-2.f * x);
    return (1.f - e) * __builtin_amdgcn_rcpf(1.f + e);
}

// ---------------- gather: X0[t*32+n][k] = bf16(emb[x[n][t]][k]) ----------------
__global__ void k_gather(const int* __restrict__ x, const float* __restrict__ emb,
                         u16* __restrict__ X0) {
    int gid = blockIdx.x * blockDim.x + threadIdx.x;
    if (gid >= 16384 * 256) return;
    int e4 = gid << 2;
    int m = e4 >> 10, k = e4 & 1023;
    int t = m >> 5, n = m & 31;
    int tok = x[n * 512 + t];
    float4 v = *reinterpret_cast<const float4*>(emb + ((size_t)tok << 10) + k);
    ushort4 o;
    o.x = f2bf(v.x); o.y = f2bf(v.y); o.z = f2bf(v.z); o.w = f2bf(v.w);
    *reinterpret_cast<ushort4*>(X0 + (size_t)e4) = o;
}

// ---------------- fp32 -> bf16 bulk convert ----------------
__global__ void k_f32bf16(const float* __restrict__ s, u16* __restrict__ d, int n4) {
    int gid = blockIdx.x * blockDim.x + threadIdx.x;
    if (gid >= n4) return;
    float4 v = reinterpret_cast<const float4*>(s)[gid];
    ushort4 o;
    o.x = f2bf(v.x); o.y = f2bf(v.y); o.z = f2bf(v.z); o.w = f2bf(v.w);
    reinterpret_cast<ushort4*>(d)[gid] = o;
}

// ---------------- GRU scan body R12 (= R9 + paired stores + fast act + prio) --
template<int LAYER>
__device__ __forceinline__ void gru_body(char* smem, int d, int wg,
    const u16* __restrict__ Gi, const u16* __restrict__ Whh_l,
    const float* __restrict__ bhh_l, u16* __restrict__ hbuf,
    u16* __restrict__ X1, float* __restrict__ hid, float* __restrict__ outp,
    u32* __restrict__ flags, u32* __restrict__ xflags, const u32* __restrict__ gdone)
{
    char* hS          = smem;                                // 32768 B (swizzled h)
    float (*ghs)[196] = (float(*)[196])(smem + 32768);       // 25088 B
    u16 (*gis)[208]   = (u16(*)[208])(smem + 57856);         // 13312 B
    float* bhh_s      = (float*)(smem + 71168);              //   768 B
    u16* hvS          = (u16*)(smem + 71936);                //  4096 B [32][64]
    const int tid = threadIdx.x;
    const int lane = tid & 63, w = tid >> 6;                 // w in [0,12)
    const int j0 = wg * 64;
    const int g = w >> 2;
    const int lr = lane & 15, lk = lane >> 4;

    __builtin_amdgcn_s_setprio(1);   // latency-critical waves outrank chasers

    if (tid < 192) {
        int g2 = tid >> 6, jj = tid & 63;
        bhh_s[tid] = bhh_l[d * 1536 + g2 * 512 + j0 + jj];
    }
    // pin W_hh fragments (16 k-tiles x 4 VGPRs = 64 VGPR/thread)
    bf16x8 wf[16];
    {
        const int joff = (w & 3) * 16;
        const u16* wr = Whh_l + (size_t)(d * 1536 + g * 512 + j0 + joff + lr) * 512 + lk * 8;
        #pragma unroll
        for (int kt = 0; kt < 16; ++kt)
            wf[kt] = *reinterpret_cast<const bf16x8*>(wr + kt * 32);
    }
    __syncthreads();

    u32* myflag = flags + (d * 8 + wg) * 32;
    const u32* wflag = flags + (d * 8 + (w & 7)) * 32;   // producer wave w polls

    // h-staging geometry (waves 0-7): lane -> (col chunk, row base)
    const int c8 = (lane & 7) * 8;       // u16 col within 64-col slice
    const int rb = lane >> 3;            // row base 0..7
    const int colu = w * 64 + c8;        // absolute u16 col (wave w slice)
    // gi-staging base chunk (waves 8-11)
    const int ci0 = (tid - 512) * 3;

    float hpv[4] = {0.f, 0.f, 0.f, 0.f};
    u32 g_seen = 0;

    for (int t = 0; t < 512; ++t) {
        // ==== A: gated parallel staging ====
        if (w < 8) {
            if (t > 0) {
                long long tt0 = __builtin_amdgcn_s_memrealtime();
                while (ld_sc01_u32(wflag) < (u32)t) {
                    __builtin_amdgcn_s_sleep(1);
                    if (__builtin_amdgcn_s_memrealtime() - tt0 > 2000) {  // 20 us
                        if (lane == 0)
                            __hip_atomic_store(myflag, (u32)t, __ATOMIC_RELEASE,
                                               __HIP_MEMORY_SCOPE_AGENT);
                        tt0 = __builtin_amdgcn_s_memrealtime();
                    }
                }
            }
            const u16* hb = hbuf + ((size_t)d * 2 + ((t + 1) & 1)) * 16384;
            u32x4 v0, v1, v2, v3;
            asm volatile("global_load_dwordx4 %0, %1, off sc0 sc1"
                         : "=v"(v0) : "v"(hb + (size_t)(rb)      * 512 + colu));
            asm volatile("global_load_dwordx4 %0, %1, off sc0 sc1"
                         : "=v"(v1) : "v"(hb + (size_t)(rb + 8)  * 512 + colu));
            asm volatile("global_load_dwordx4 %0, %1, off sc0 sc1"
                         : "=v"(v2) : "v"(hb + (size_t)(rb + 16) * 512 + colu));
            asm volatile("global_load_dwordx4 %0, %1, off sc0 sc1"
                         : "=v"(v3) : "v"(hb + (size_t)(rb + 24) * 512 + colu));
            asm volatile("s_waitcnt vmcnt(0)" ::: "memory");
            const int cb = colu * 2;
            *reinterpret_cast<u32x4*>(hS + (rb)      * 1024 + (cb ^ (((rb)      & 15) << 4))) = v0;
            *reinterpret_cast<u32x4*>(hS + (rb + 8)  * 1024 + (cb ^ (((rb + 8)  & 15) << 4))) = v1;
            *reinterpret_cast<u32x4*>(hS + (rb + 16) * 1024 + (cb ^ (((rb + 16) & 15) << 4))) = v2;
            *reinterpret_cast<u32x4*>(hS + (rb + 24) * 1024 + (cb ^ (((rb + 24) & 15) << 4))) = v3;
        } else {
            u32 yneed = (u32)(t >> 2);
            if (g_seen <= yneed) {
                const u32* gp = gdone + yneed;
                long long T0 = __builtin_amdgcn_s_memrealtime();
                while (ld_sc01_u32(gp) == 0) {
                    __builtin_amdgcn_s_sleep(1);
                    if (__builtin_amdgcn_s_memrealtime() - T0 > 2000000) break;  // 20 ms
                }
                g_seen = yneed + 1;
            }
            u32x4 gq[3];
            int nbs[3], gcs[3];
            #pragma unroll
            for (int i = 0; i < 3; ++i) {
                int ci = ci0 + i;
                nbs[i] = ci / 24; gcs[i] = ci % 24;
                const u16* gp = Gi + (size_t)(t * 32 + nbs[i]) * 3072 + d * 1536
                              + (gcs[i] >> 3) * 512 + j0 + (gcs[i] & 7) * 8;
                asm volatile("global_load_dwordx4 %0, %1, off sc0 sc1"
                             : "=v"(gq[i]) : "v"(gp));
            }
            asm volatile("s_waitcnt vmcnt(0)" ::: "memory");
            #pragma unroll
            for (int i = 0; i < 3; ++i)
                *reinterpret_cast<u32x4*>(&gis[nbs[i]][gcs[i] * 8]) = gq[i];
        }
        __syncthreads();   // B1: hS + gis staged

        // ==== B: MFMA + ghs ====
        f32x4 acc0 = {0.f, 0.f, 0.f, 0.f}, acc1 = acc0;
        #pragma unroll
        for (int kt = 0; kt < 16; ++kt) {
            int boff = (lk * 16 + kt * 64) ^ (lr << 4);
            bf16x8 a0 = *reinterpret_cast<const bf16x8*>(hS + lr * 1024 + boff);
            bf16x8 a1 = *reinterpret_cast<const bf16x8*>(hS + (16 + lr) * 1024 + boff);
            acc0 = __builtin_amdgcn_mfma_f32_16x16x32_bf16(a0, wf[kt], acc0, 0, 0, 0);
            acc1 = __builtin_amdgcn_mfma_f32_16x16x32_bf16(a1, wf[kt], acc1, 0, 0, 0);
        }
        int colg = w * 16 + lr;
        float bv = bhh_s[colg];
        #pragma unroll
        for (int q = 0; q < 4; ++q) {
            ghs[lk * 4 + q][colg]      = acc0[q] + bv;
            ghs[16 + lk * 4 + q][colg] = acc1[q] + bv;
        }
        __syncthreads();   // B2: ghs ready

        // ==== C: gates + h' (paired u32 stores; fast activations) ====
        u16* hbw = hbuf + ((size_t)d * 2 + (t & 1)) * 16384;
        #pragma unroll
        for (int rep = 0; rep < 2; ++rep) {
            int e2 = tid + rep * 768;
            if (e2 < 1024) {
                int jp = (e2 & 31) * 2, nb = e2 >> 5;
                int rr = rep * 2;
                float r0 = sigm(bf2f(gis[nb][jp])          + ghs[nb][jp]);
                float r1 = sigm(bf2f(gis[nb][jp + 1])      + ghs[nb][jp + 1]);
                float z0 = sigm(bf2f(gis[nb][64 + jp])     + ghs[nb][64 + jp]);
                float z1 = sigm(bf2f(gis[nb][64 + jp + 1]) + ghs[nb][64 + jp + 1]);
                float n0 = tanh_fast(bf2f(gis[nb][128 + jp])     + r0 * ghs[nb][128 + jp]);
                float n1 = tanh_fast(bf2f(gis[nb][128 + jp + 1]) + r1 * ghs[nb][128 + jp + 1]);
                float hv0 = (1.f - z0) * n0 + z0 * hpv[rr];
                float hv1 = (1.f - z1) * n1 + z1 * hpv[rr + 1];
                hpv[rr] = hv0; hpv[rr + 1] = hv1;
                u32 packed = (u32)f2bf(hv0) | ((u32)f2bf(hv1) << 16);
                st_sc01_u32((u32*)(hbw + (size_t)nb * 512 + j0 + jp), packed);
                *reinterpret_cast<u32*>(hvS + nb * 64 + jp) = packed;
            }
        }
        asm volatile("s_waitcnt vmcnt(0)" ::: "memory");   // h stores acked at LLC
        __syncthreads();   // B3
        if (tid == 16)
            st_sc01_u32(myflag, (u32)(t + 1));

        // ==== D: deferred outputs, tid>=512 (from hvS) ====
        if (tid >= 512) {
            int q = tid - 512, nb = q >> 3, j8 = (q & 7) * 8;
            union { u32x4 v; u16 s[8]; } h8;
            h8.v = *reinterpret_cast<const u32x4*>(hvS + nb * 64 + j8);
            float f0 = bf2f(h8.s[0]), f1 = bf2f(h8.s[1]), f2 = bf2f(h8.s[2]), f3 = bf2f(h8.s[3]);
            float f4 = bf2f(h8.s[4]), f5 = bf2f(h8.s[5]), f6 = bf2f(h8.s[6]), f7 = bf2f(h8.s[7]);
            float* hp = hid + ((size_t)(t * 4 + LAYER * 2 + d) * 32 + nb) * 512 + j0 + j8;
            *reinterpret_cast<float4*>(hp)     = make_float4(f0, f1, f2, f3);
            *reinterpret_cast<float4*>(hp + 4) = make_float4(f4, f5, f6, f7);
            if (LAYER == 0) {
                u16* xp = X1 + (size_t)(t * 32 + nb) * 1024 + (size_t)d * 512 + j0 + j8;
                st_sc01_u32x4(xp, h8.v);
            } else {
                float* op = outp + ((size_t)nb * 512 + t) * 1024 + (size_t)d * 512 + j0 + j8;
                *reinterpret_cast<float4*>(op)     = make_float4(f0, f1, f2, f3);
                *reinterpret_cast<float4*>(op + 4) = make_float4(f4, f5, f6, f7);
            }
        }
        // ==== E: X1 visibility flag at chaser granularity (every 4 steps) ====
        if (LAYER == 0 && (t & 3) == 3) {
            asm volatile("s_waitcnt vmcnt(0)" ::: "memory");  // X1 at LLC
            __syncthreads();
            if (tid == 17)
                st_sc01_u32(xflags + (d * 8 + wg) * 32, (u32)(t + 1));
        }
    }
}

// ---------------- chaser GEMM (48 WGs per phase; waves 0-5 compute) ----------
__device__ __forceinline__ void chaser_body(char* smem, int cw,
    const u16* __restrict__ A, const u16* __restrict__ B,
    const float* __restrict__ bias, u16* __restrict__ Gi,
    const u32* __restrict__ xflags, u32* __restrict__ cnt, u32* __restrict__ done)
{
    u16* As = (u16*)smem;            // 16 KB
    u16* Bs = (u16*)(smem + 16384);  // 12 KB
    const int tid = threadIdx.x;
    const int lane = tid & 63, wid = tid >> 6;
    const int wm = wid & 1, wn = wid >> 1;
    const int lr = lane & 15, lk = lane >> 4;

    for (int T = cw; T < 4096; T += 48) {
        const int y = T >> 5, x = T & 31;
        if (xflags && tid < 16) {
            const u32* fp = xflags + tid * 32;
            u32 target = 4u * (u32)y + 4u;
            long long T0 = __builtin_amdgcn_s_memrealtime();
            while (ld_sc01_u32(fp) < target) {
                __builtin_amdgcn_s_sleep(4);
                if (__builtin_amdgcn_s_memrealtime() - T0 > 2000000) break;  // 20 ms
            }
        }
        __syncthreads();

        f32x4 zero = {0.f, 0.f, 0.f, 0.f};
        f32x4 acc[4][2];
        #pragma unroll
        for (int i = 0; i < 4; ++i) { acc[i][0] = zero; acc[i][1] = zero; }

        for (int k0 = 0; k0 < 1024; k0 += 64) {
            #pragma unroll
            for (int r = 0; r < 5; ++r) {
                int c = wid * 5 + r;               // wid>=6 -> c>=30 -> skipped
                if (c < 16) {
                    int o = c * 1024 + lane * 16;
                    int row = o >> 7, kb = o & 127;
                    int kbs = kb ^ ((row & 7) << 4);
                    const char* s = (const char*)A + ((size_t)(y * 128 + row) * 1024 + k0) * 2 + kbs;
                    __builtin_amdgcn_global_load_lds(GLP(s), LDSP((char*)As + c * 1024), 16, 0, 0);
                } else if (c < 28) {
                    int c2 = c - 16;
                    int o = c2 * 1024 + lane * 16;
                    int row = o >> 7, kb = o & 127;
                    int kbs = kb ^ ((row & 7) << 4);
                    const char* s = (const char*)B + ((size_t)(x * 96 + row) * 1024 + k0) * 2 + kbs;
                    __builtin_amdgcn_global_load_lds(GLP(s), LDSP((char*)Bs + c2 * 1024), 16, 0, 0);
                }
            }
            __syncthreads();
            if (wid < 6) {
                #pragma unroll
                for (int kk = 0; kk < 2; ++kk) {
                    bf16x8 af[4], bfr[2];
                    int kb = kk * 64 + lk * 16;
                    #pragma unroll
                    for (int i = 0; i < 4; ++i) {
                        int rowA = wm * 64 + i * 16 + lr;
                        af[i] = *reinterpret_cast<const bf16x8*>((const char*)As + rowA * 128 + (kb ^ ((rowA & 7) << 4)));
                    }
                    #pragma unroll
                    for (int j = 0; j < 2; ++j) {
                        int rowB = wn * 32 + j * 16 + lr;
                        bfr[j] = *reinterpret_cast<const bf16x8*>((const char*)Bs + rowB * 128 + (kb ^ ((rowB & 7) << 4)));
                    }
                    #pragma unroll
                    for (int i = 0; i < 4; ++i)
                        #pragma unroll
                        for (int j = 0; j < 2; ++j)
                            acc[i][j] = __builtin_amdgcn_mfma_f32_16x16x32_bf16(af[i], bfr[j], acc[i][j], 0, 0, 0);
                }
            }
            __syncthreads();
        }
        if (wid < 6) {
            #pragma unroll
            for (int j = 0; j < 2; ++j) {
                int col = x * 96 + wn * 32 + j * 16 + lr;
                float bv = bias[col];
                #pragma unroll
                for (int i = 0; i < 4; ++i) {
                    int rowb = y * 128 + wm * 64 + i * 16 + lk * 4;
                    #pragma unroll
                    for (int q = 0; q < 4; ++q)
                        st_sc01_u16(Gi + (size_t)(rowb + q) * 3072 + col, f2bf(acc[i][j][q] + bv));
                }
            }
        }
        asm volatile("s_waitcnt vmcnt(0)" ::: "memory");
        __syncthreads();
        if (tid == 0) {
            u32 old = __hip_atomic_fetch_add(&cnt[y], 1u, __ATOMIC_RELAXED,
                                             __HIP_MEMORY_SCOPE_AGENT);
            if (old == 31u)
                st_sc01_u32((u32*)&done[y], 1u);
        }
    }
}

// -------- fused: gru0(16) | gemm0-chaser(48) | gemm1-chaser(48) | gru1(16) ----
__global__ __launch_bounds__(768, 2) void k_fused(
    u16* __restrict__ Gi,
    const u16* __restrict__ X0, const u16* __restrict__ Wih,
    const float* __restrict__ b_ih,
    const u16* __restrict__ Whh, const float* __restrict__ bhh,
    u16* __restrict__ hbuf0, u16* __restrict__ hbuf1,
    u16* __restrict__ X1,
    float* __restrict__ hid, float* __restrict__ outp,
    u32* __restrict__ flags0, u32* __restrict__ flags1,
    u32* __restrict__ xflags,
    u32* __restrict__ g0cnt, u32* __restrict__ g0done,
    u32* __restrict__ g1cnt, u32* __restrict__ g1done)
{
    __shared__ __align__(16) char smem[76032];
    int bid = blockIdx.x;
    if (bid < 16) {
        gru_body<0>(smem, bid >> 3, bid & 7, Gi, Whh, bhh, hbuf0,
                    X1, hid, outp, flags0, xflags, g0done);
    } else if (bid < 64) {
        chaser_body(smem, bid - 16, X0, Wih, b_ih, Gi, nullptr, g0cnt, g0done);
    } else if (bid < 112) {
        chaser_body(smem, bid - 64, X1, Wih + (size_t)3072 * 1024, b_ih + 3072,
                    Gi, xflags, g1cnt, g1done);
    } else {
        int b = bid - 112;
        gru_body<1>(smem, b >> 3, b & 7, Gi, Whh + (size_t)3072 * 512, bhh + 3072,
                    hbuf1, nullptr, hid, outp, flags1, nullptr, g1done);
    }
}

extern "C" void kernel_launch(void* const* d_in, const int* in_sizes, int n_in,
                              void* d_out, int out_size, void* d_ws, size_t ws_size,
                              hipStream_t stream) {
    const int*   x    = (const int*)d_in[0];
    const float* emb  = (const float*)d_in[1];
    const float* w_ih = (const float*)d_in[2];
    const float* w_hh = (const float*)d_in[3];
    const float* b_ih = (const float*)d_in[4];
    const float* b_hh = (const float*)d_in[5];
    float* outp = (float*)d_out;
    float* hid  = outp + (size_t)32 * 512 * 1024;

    char* ws = (char*)d_ws;
    u16* X0     = (u16*)(ws);                  //  33,554,432 B
    u16* X1     = (u16*)(ws + 33554432);       //  33,554,432 B
    u16* Wih    = (u16*)(ws + 67108864);       //  12,582,912 B
    u16* Whh    = (u16*)(ws + 79691776);       //   6,291,456 B
    u16* Gi     = (u16*)(ws + 85983232);       // 100,663,296 B
    u16* hbuf0  = (u16*)(ws + 186646528);      //     131,072 B
    u16* hbuf1  = (u16*)(ws + 186777600);      //     131,072 B
    u32* flags0 = (u32*)(ws + 186908672);      //       2,048 B  [2][8][32]
    u32* flags1 = (u32*)(ws + 186910720);      //       2,048 B
    u32* xflags = (u32*)(ws + 186912768);      //       2,048 B  [2][8][32]
    u32* g0cnt  = (u32*)(ws + 186914816);      //         512 B
    u32* g0done = (u32*)(ws + 186915328);      //         512 B
    u32* g1cnt  = (u32*)(ws + 186915840);      //         512 B
    u32* g1done = (u32*)(ws + 186916352);      //         512 B

    k_gather<<<16384, 256, 0, stream>>>(x, emb, X0);
    k_f32bf16<<<(1572864 + 255) / 256, 256, 0, stream>>>(w_ih, Wih, 1572864);
    k_f32bf16<<<( 786432 + 255) / 256, 256, 0, stream>>>(w_hh, Whh, 786432);

    // zero hbuf0|hbuf1|flags0|flags1|xflags|g0cnt|g0done|g1cnt|g1done (contiguous)
    (void)hipMemsetAsync(hbuf0, 0, 270336, stream);

    // fused pipeline: gru0 | gemm0-chaser | gemm1-chaser | gru1
    k_fused<<<128, 768, 0, stream>>>(Gi, X0, Wih, b_ih, Whh, b_hh,
                                     hbuf0, hbuf1, X1, hid, outp,
                                     flags0, flags1, xflags,
                                     g0cnt, g0done, g1cnt, g1done);
}